// Round 18
// baseline (287.615 us; speedup 1.0000x reference)
//
#include <hip/hip_runtime.h>
#include <hip/hip_bf16.h>
#include <math.h>

#define TT 1024
#define DD 1024
#define HH 16
#define KVHN 4
#define HDW 64
#define DFFN 4096
#define WIN 256

typedef __attribute__((ext_vector_type(4))) float f32x4;
typedef __attribute__((ext_vector_type(8))) __bf16 bf16x8;

typedef const __attribute__((address_space(1))) void gas_t;
typedef __attribute__((address_space(3))) void las_t;

__device__ inline unsigned short f2bf(float f){
  union { float f; unsigned u; } x; x.f = f;
  unsigned r = x.u + 0x7fffu + ((x.u >> 16) & 1u);
  return (unsigned short)(r >> 16);
}
__device__ inline float bf2f(unsigned short b){
  union { unsigned u; float f; } x; x.u = ((unsigned)b) << 16; return x.f;
}
__device__ inline f32x4 MFMA(bf16x8 a, bf16x8 b, f32x4 c){
  return __builtin_amdgcn_mfma_f32_16x16x32_bf16(a, b, c, 0, 0, 0);
}

__global__ void zero_k(float* out, int n){
  for (int i = blockIdx.x * blockDim.x + threadIdx.x; i < n; i += gridDim.x * blockDim.x)
    out[i] = 0.f;
}

// ---------- weight transpose: W[K][N] fp32 -> Wt[N][K] bf16 ----------
__global__ __launch_bounds__(256) void wtrans_k(const float* __restrict__ W,
                                                unsigned short* __restrict__ Wt,
                                                int K, int N){
  __shared__ float t[32][33];
  int n0 = blockIdx.x * 32, k0 = blockIdx.y * 32;
  int tx = threadIdx.x & 31, ty = threadIdx.x >> 5;
#pragma unroll
  for (int i = 0; i < 4; i++){
    int kk = ty * 4 + i;
    t[kk][tx] = W[(size_t)(k0 + kk) * N + n0 + tx];
  }
  __syncthreads();
#pragma unroll
  for (int i = 0; i < 4; i++){
    int nn = ty * 4 + i;
    Wt[(size_t)(n0 + nn) * K + k0 + tx] = f2bf(t[tx][nn]);
  }
}

// ---------- pack QKV bias ----------
__global__ void packb_k(const float* bq, const float* bk, const float* bv, float* o){
  int i = blockIdx.x * 256 + threadIdx.x;
  if (i < 1536)
    o[i] = (i < 1024) ? bq[i] : ((i < 1280) ? bk[i - 1024] : bv[i - 1280]);
}

// ---------- dst = src + bias (row-broadcast), fp32, vectorized ----------
__global__ __launch_bounds__(256) void resadd_k(const float* __restrict__ src,
                                                const float* __restrict__ bias,
                                                float* __restrict__ dst){
  for (int i = blockIdx.x * blockDim.x + threadIdx.x; i < (4096 * 1024) / 4;
       i += gridDim.x * blockDim.x){
    float4 s = ((const float4*)src)[i];
    float4 b = ((const float4*)bias)[i & 255];
    s.x += b.x; s.y += b.y; s.z += b.z; s.w += b.w;
    ((float4*)dst)[i] = s;
  }
}

// ---------- layernorm: fp32 row -> bf16 row ----------
__global__ __launch_bounds__(256) void ln_k(const float* __restrict__ x,
                                            const float* __restrict__ g,
                                            const float* __restrict__ b,
                                            unsigned short* __restrict__ out){
  __shared__ float red[4];
  int row = blockIdx.x, tid = threadIdx.x;
  const float* xr = x + (size_t)row * DD;
  float4 v = *(const float4*)(xr + tid * 4);
  float s = v.x + v.y + v.z + v.w;
#pragma unroll
  for (int off = 32; off; off >>= 1) s += __shfl_xor(s, off);
  if ((tid & 63) == 0) red[tid >> 6] = s;
  __syncthreads();
  float mu = (red[0] + red[1] + red[2] + red[3]) * (1.f / DD);
  __syncthreads();
  float dx = v.x - mu, dy = v.y - mu, dz = v.z - mu, dw = v.w - mu;
  float sq = dx*dx + dy*dy + dz*dz + dw*dw;
#pragma unroll
  for (int off = 32; off; off >>= 1) sq += __shfl_xor(sq, off);
  if ((tid & 63) == 0) red[tid >> 6] = sq;
  __syncthreads();
  float var = (red[0] + red[1] + red[2] + red[3]) * (1.f / DD);
  float inv = rsqrtf(var + 1e-5f);
  float4 gv = *(const float4*)(g + tid * 4);
  float4 bv = *(const float4*)(b + tid * 4);
  unsigned short* orow = out + (size_t)row * DD + tid * 4;
  orow[0] = f2bf(dx * inv * gv.x + bv.x);
  orow[1] = f2bf(dy * inv * gv.y + bv.y);
  orow[2] = f2bf(dz * inv * gv.z + bv.z);
  orow[3] = f2bf(dw * inv * gv.w + bv.w);
}

// ---------- 128x128 BK=32 GEMM, T4 counted-vmcnt, 3-slot rotation ----------
// Per iter t: issue tile t+2 -> slot (t+2)%3; s_waitcnt vmcnt(8) [8 newer loads
// stay in flight]; s_barrier; ds_read slot t%3 + 16 MFMA; s_barrier (no drain).
// Conflict-free swizzle (r17-verified): chunk c of row R at pos c^((R>>1)&3).
// EPI 0: bf16. 1: GELU bf16. 2: +res fp32. 5: unsafeAtomicAdd fp32 (no bias).
template<int EPI>
__global__ __launch_bounds__(256, 3) void gemm32_k(const unsigned short* __restrict__ A,
                                                   const unsigned short* __restrict__ Bt,
                                                   const float* __restrict__ bias,
                                                   const float* __restrict__ res,
                                                   void* __restrict__ Cout,
                                                   int M, int N, int Klen, int lda, int ldb){
  __shared__ unsigned short As[3][4096];
  __shared__ unsigned short Bs[3][4096];
  int tid = threadIdx.x;
  int row0 = blockIdx.x * 128, col0 = blockIdx.y * 128;
  A  += (size_t)blockIdx.z * Klen;
  Bt += (size_t)blockIdx.z * Klen;
  int wid = tid >> 6, lane = tid & 63;
  int wm = (wid >> 1) * 64, wn = (wid & 1) * 64;
  int lr = lane & 15, lg = lane >> 4;
  f32x4 acc[4][4] = {};

  int srow = tid >> 2;                               // 0..63
  int scol = ((tid & 3) ^ ((srow >> 1) & 3)) * 8;    // pre-swizzled source chunk
  const unsigned short* gA0 = A  + (size_t)(row0 + srow) * lda + scol;
  const unsigned short* gB0 = Bt + (size_t)(col0 + srow) * ldb + scol;
  int lbase = wid * 512;                             // ushorts

  auto stage = [&](int slot, int tile){
    int k0 = tile << 5;
#pragma unroll
    for (int j = 0; j < 2; j++){
      __builtin_amdgcn_global_load_lds((gas_t*)(gA0 + (size_t)(j*64)*lda + k0), (las_t*)&As[slot][j*2048 + lbase], 16, 0, 0);
      __builtin_amdgcn_global_load_lds((gas_t*)(gB0 + (size_t)(j*64)*ldb + k0), (las_t*)&Bs[slot][j*2048 + lbase], 16, 0, 0);
    }
  };

  int NT = Klen >> 5;
  // prologue: depth-2 prefetch
  stage(0, 0);
  if (NT > 1) stage(1, 1);
  int sl = 0;
  for (int t = 0; t < NT; t++){
    if (t + 2 < NT){
      int s2 = sl + 2; if (s2 >= 3) s2 -= 3;
      stage(s2, t + 2);
      asm volatile("s_waitcnt vmcnt(8)" ::: "memory");
    } else if (t + 1 < NT){
      asm volatile("s_waitcnt vmcnt(4)" ::: "memory");
    } else {
      asm volatile("s_waitcnt vmcnt(0)" ::: "memory");
    }
    __builtin_amdgcn_sched_barrier(0);
    __builtin_amdgcn_s_barrier();
    __builtin_amdgcn_sched_barrier(0);
    bf16x8 af[4], bf[4];
#pragma unroll
    for (int mt = 0; mt < 4; mt++){
      int R = wm + mt*16 + lr;
      af[mt] = *(const bf16x8*)&As[sl][R * 32 + ((lg ^ ((R >> 1) & 3)) << 3)];
    }
#pragma unroll
    for (int nt2 = 0; nt2 < 4; nt2++){
      int R = wn + nt2*16 + lr;
      bf[nt2] = *(const bf16x8*)&Bs[sl][R * 32 + ((lg ^ ((R >> 1) & 3)) << 3)];
    }
#pragma unroll
    for (int mt = 0; mt < 4; mt++)
#pragma unroll
      for (int nt2 = 0; nt2 < 4; nt2++)
        acc[mt][nt2] = MFMA(af[mt], bf[nt2], acc[mt][nt2]);
    __builtin_amdgcn_sched_barrier(0);
    __builtin_amdgcn_s_barrier();    // all waves done reading slot sl (no drain)
    sl++; if (sl >= 3) sl -= 3;
  }
#pragma unroll
  for (int mt = 0; mt < 4; mt++){
#pragma unroll
    for (int r = 0; r < 4; r++){
      int gr = row0 + wm + mt*16 + lg*4 + r;
#pragma unroll
      for (int nt2 = 0; nt2 < 4; nt2++){
        int gc = col0 + wn + nt2*16 + lr;
        if constexpr (EPI == 5){
          unsafeAtomicAdd(&((float*)Cout)[(size_t)gr * N + gc], acc[mt][nt2][r]);
        } else {
          float val = acc[mt][nt2][r] + bias[gc];
          if constexpr (EPI == 1){
            val = 0.5f * val * (1.f + erff(val * 0.70710678118f));
          }
          if constexpr (EPI == 2){
            float ov = val + res[(size_t)gr * N + gc];
            ((float*)Cout)[(size_t)gr * N + gc] = ov;
          } else {
            ((unsigned short*)Cout)[(size_t)gr * N + gc] = f2bf(val);
          }
        }
      }
    }
  }
}

// ---------- RoPE in-place, NEGATED rotation (verified r8), strided rows ----------
template<int NH>
__global__ __launch_bounds__(256) void rope_k(unsigned short* base, int rs){
  int idx = blockIdx.x * 8 + (threadIdx.x >> 5);
  int d = threadIdx.x & 31;
  int row = idx / NH;          // b*T + t
  int head = idx % NH;
  int t = row & (TT - 1);
  unsigned short* p = base + (size_t)row * rs + head * HDW;
  float x1 = bf2f(p[d]);
  float x2 = bf2f(p[d + 32]);
  float theta = powf(10000.f, -(float)d * (1.f / 32.f));
  float c, s;
  sincosf((float)t * theta, &c, &s);
  p[d]      = f2bf(x1 * c + x2 * s);
  p[d + 32] = f2bf(x2 * c - x1 * s);
}

// ---------- V transpose: packed v rows (stride rs) -> vt[b][kvh][d][t] ----------
__global__ __launch_bounds__(256) void vtrans_k(const unsigned short* __restrict__ v, int rs,
                                                unsigned short* __restrict__ vt){
  __shared__ unsigned short tile[64][72];
  int t0 = blockIdx.x * 64;
  int kvh = blockIdx.y, b = blockIdx.z;
  int i = threadIdx.x;
  int tl = i >> 2, dc = (i & 3) * 16;
  const unsigned short* src = v + (size_t)(b * TT + t0 + tl) * rs + kvh * HDW + dc;
  *(uint4*)&tile[tl][dc]     = *(const uint4*)src;
  *(uint4*)&tile[tl][dc + 8] = *(const uint4*)(src + 8);
  __syncthreads();
  int d = i >> 2, tc = (i & 3) * 16;
  unsigned short tmp[16];
#pragma unroll
  for (int e = 0; e < 16; e++) tmp[e] = tile[tc + e][d];
  unsigned short* dst = vt + ((size_t)((b * KVHN + kvh) * HDW) + d) * TT + t0 + tc;
  *(uint4*)dst       = *(uint4*)tmp;
  *(uint4*)(dst + 8) = *(uint4*)(tmp + 8);
}

// ---------- flash attention, 1 wave per (b, h, 32-row q-tile); strided q/k ----------
__global__ __launch_bounds__(64) void attn_k(const unsigned short* __restrict__ q, int qrs,
                                             const unsigned short* __restrict__ k, int krs,
                                             const unsigned short* __restrict__ vt,
                                             unsigned short* __restrict__ o){
  __shared__ unsigned short P[32 * 40];
  __shared__ float sc_l[32];
  int qt = blockIdx.x, h = blockIdx.y, b = blockIdx.z;
  int kvh = h >> 2;
  int lane = threadIdx.x;
  int lr = lane & 15, lg = lane >> 4;
  int q0 = qt * 32;
  bf16x8 qf[2][2];
#pragma unroll
  for (int qi = 0; qi < 2; qi++)
#pragma unroll
    for (int ks = 0; ks < 2; ks++)
      qf[qi][ks] = *(const bf16x8*)(q + (size_t)(b*TT + q0 + qi*16 + lr) * qrs + h * HDW + ks*32 + lg*8);
  f32x4 oa[2][4] = {};
  float m_st[2] = {-1e30f, -1e30f};
  float l_st[2] = {0.f, 0.f};
  int kt_lo = (q0 - (WIN - 1)) > 0 ? ((q0 - (WIN - 1)) >> 5) : 0;
  int kt_hi = (q0 + 31) >> 5;
  for (int kt = kt_lo; kt <= kt_hi; kt++){
    int kb = kt * 32;
    bf16x8 kf[2][2];
#pragma unroll
    for (int ki = 0; ki < 2; ki++)
#pragma unroll
      for (int ks = 0; ks < 2; ks++)
        kf[ki][ks] = *(const bf16x8*)(k + (size_t)(b*TT + kb + ki*16 + lr) * krs + kvh * HDW + ks*32 + lg*8);
    f32x4 s[2][2] = {};
#pragma unroll
    for (int ki = 0; ki < 2; ki++)
#pragma unroll
      for (int qi = 0; qi < 2; qi++){
        s[ki][qi] = MFMA(kf[ki][0], qf[qi][0], s[ki][qi]);
        s[ki][qi] = MFMA(kf[ki][1], qf[qi][1], s[ki][qi]);
      }
#pragma unroll
    for (int qi = 0; qi < 2; qi++){
      int qa = q0 + qi*16 + lr;
      float pv[8];
      float mx = -1e30f;
#pragma unroll
      for (int ki = 0; ki < 2; ki++)
#pragma unroll
        for (int r = 0; r < 4; r++){
          int ka = kb + ki*16 + lg*4 + r;
          float val = s[ki][qi][r] * 0.125f;
          bool ok = (ka <= qa) && (qa - ka < WIN);
          val = ok ? val : -1e9f;
          pv[ki*4 + r] = val;
          mx = fmaxf(mx, val);
        }
      mx = fmaxf(mx, __shfl_xor(mx, 16));
      mx = fmaxf(mx, __shfl_xor(mx, 32));
      float mn = fmaxf(m_st[qi], mx);
      float scl = __expf(m_st[qi] - mn);
      m_st[qi] = mn;
      float ls = 0.f;
#pragma unroll
      for (int j = 0; j < 8; j++){ float p = __expf(pv[j] - mn); pv[j] = p; ls += p; }
      ls += __shfl_xor(ls, 16);
      ls += __shfl_xor(ls, 32);
      l_st[qi] = l_st[qi] * scl + ls;
#pragma unroll
      for (int ki = 0; ki < 2; ki++){
        uint2 w;
        w.x = (unsigned)f2bf(pv[ki*4+0]) | ((unsigned)f2bf(pv[ki*4+1]) << 16);
        w.y = (unsigned)f2bf(pv[ki*4+2]) | ((unsigned)f2bf(pv[ki*4+3]) << 16);
        *(uint2*)&P[(qi*16 + lr) * 40 + ki*16 + lg*4] = w;
      }
      if (lg == 0) sc_l[qi*16 + lr] = scl;
    }
    __syncthreads();
#pragma unroll
    for (int qi = 0; qi < 2; qi++)
#pragma unroll
      for (int r = 0; r < 4; r++){
        float f = sc_l[qi*16 + lg*4 + r];
#pragma unroll
        for (int di = 0; di < 4; di++) oa[qi][di][r] *= f;
      }
    bf16x8 pa[2];
#pragma unroll
    for (int qi = 0; qi < 2; qi++)
      pa[qi] = *(const bf16x8*)&P[(qi*16 + lr) * 40 + lg*8];
#pragma unroll
    for (int di = 0; di < 4; di++){
      bf16x8 vb = *(const bf16x8*)(vt + ((size_t)((b*KVHN + kvh) * HDW) + di*16 + lr) * TT + kb + lg*8);
#pragma unroll
      for (int qi = 0; qi < 2; qi++)
        oa[qi][di] = MFMA(pa[qi], vb, oa[qi][di]);
    }
    __syncthreads();
  }
  if (lg == 0){ sc_l[lr] = l_st[0]; sc_l[16 + lr] = l_st[1]; }
  __syncthreads();
#pragma unroll
  for (int qi = 0; qi < 2; qi++)
#pragma unroll
    for (int r = 0; r < 4; r++){
      float inv = 1.f / sc_l[qi*16 + lg*4 + r];
      int t = q0 + qi*16 + lg*4 + r;
#pragma unroll
      for (int di = 0; di < 4; di++)
        o[((size_t)((b*TT + t) * HH) + h) * HDW + di*16 + lr] = f2bf(oa[qi][di][r] * inv);
    }
}

extern "C" void kernel_launch(void* const* d_in, const int* in_sizes, int n_in,
                              void* d_out, int out_size, void* d_ws, size_t ws_size,
                              hipStream_t stream){
  const float* x   = (const float*)d_in[0];
  const float* Wq  = (const float*)d_in[1];
  const float* bq  = (const float*)d_in[2];
  const float* Wk  = (const float*)d_in[3];
  const float* bk  = (const float*)d_in[4];
  const float* Wv  = (const float*)d_in[5];
  const float* bv  = (const float*)d_in[6];
  const float* Wo  = (const float*)d_in[7];
  const float* bo  = (const float*)d_in[8];
  const float* g1  = (const float*)d_in[9];
  const float* b1  = (const float*)d_in[10];
  const float* Wf1 = (const float*)d_in[11];
  const float* bf1 = (const float*)d_in[12];
  const float* Wf2 = (const float*)d_in[13];
  const float* bf2 = (const float*)d_in[14];
  const float* g2  = (const float*)d_in[15];
  const float* b2  = (const float*)d_in[16];

  static const int want[17] = {4194304, 1048576, 1024, 262144, 256, 262144, 256,
                               1048576, 1024, 1024, 1024, 4194304, 4096, 4194304,
                               1024, 1024, 1024};
  bool bad = (n_in != 17) || (out_size != 4194304);
  if (!bad) for (int i = 0; i < 17; i++) if (in_sizes[i] != want[i]) bad = true;
  if (bad){
    zero_k<<<2048, 256, 0, stream>>>((float*)d_out, out_size);
    return;
  }

  const int M = 4 * TT;       // 4096 rows
  const int QKVN = 1536;      // packed q|k|v width
  char* ws = (char*)d_ws;
  size_t off = 0;
  auto alloc = [&](size_t bytes) -> void* {
    void* p = ws + off; off += (bytes + 255) & ~(size_t)255; return p;
  };
  unsigned short* wqkv = (unsigned short*)alloc((size_t)QKVN * DD * 2);
  unsigned short* wto  = (unsigned short*)alloc((size_t)DD * DD * 2);
  unsigned short* wtf1 = (unsigned short*)alloc((size_t)DFFN * DD * 2);
  unsigned short* wtf2 = (unsigned short*)alloc((size_t)DD * DFFN * 2);
  float*          bqkv = (float*)alloc((size_t)QKVN * 4);
  unsigned short* h1   = (unsigned short*)alloc((size_t)M * DD * 2);
  unsigned short* qkv  = (unsigned short*)alloc((size_t)M * QKVN * 2);
  unsigned short* vtb  = (unsigned short*)alloc((size_t)M * 256 * 2);
  unsigned short* ao   = (unsigned short*)alloc((size_t)M * DD * 2);
  float*          x2   = (float*)alloc((size_t)M * DD * 4);
  unsigned short* h2   = h1;            // reuse
  unsigned short* ff   = (unsigned short*)alloc((size_t)M * DFFN * 2);
  (void)ws_size;

  // weights -> bf16 transposed (QKV packed)
  wtrans_k<<<dim3(DD/32,  DD/32),  256, 0, stream>>>(Wq,  wqkv,                       DD,  DD);
  wtrans_k<<<dim3(256/32, DD/32),  256, 0, stream>>>(Wk,  wqkv + (size_t)1024 * DD,   DD,  256);
  wtrans_k<<<dim3(256/32, DD/32),  256, 0, stream>>>(Wv,  wqkv + (size_t)1280 * DD,   DD,  256);
  wtrans_k<<<dim3(DD/32,  DD/32),  256, 0, stream>>>(Wo,  wto,  DD,  DD);
  wtrans_k<<<dim3(DFFN/32,DD/32),  256, 0, stream>>>(Wf1, wtf1, DD,  DFFN);
  wtrans_k<<<dim3(DD/32,  DFFN/32),256, 0, stream>>>(Wf2, wtf2, DFFN,DD);
  packb_k<<<6, 256, 0, stream>>>(bq, bk, bv, bqkv);

  // LN1
  ln_k<<<M, 256, 0, stream>>>(x, g1, b1, h1);

  // QKV fused (T4 counted-vmcnt)
  gemm32_k<0><<<dim3(M/128, QKVN/128), 256, 0, stream>>>(h1, wqkv, bqkv, nullptr, qkv, M, QKVN, DD, DD, DD);

  // RoPE on packed buffer
  rope_k<HH>  <<<(M * HH) / 8,   256, 0, stream>>>(qkv,        QKVN);
  rope_k<KVHN><<<(M * KVHN) / 8, 256, 0, stream>>>(qkv + 1024, QKVN);

  // V transpose
  vtrans_k<<<dim3(TT/64, KVHN, 4), 256, 0, stream>>>(qkv + 1280, QKVN, vtb);

  // attention
  attn_k<<<dim3(TT/32, HH, 4), 64, 0, stream>>>(qkv, QKVN, qkv + 1024, QKVN, vtb, ao);

  // Wo: x2 = x + bo, then split-K2 atomic accumulate of ao@wto
  resadd_k<<<2048, 256, 0, stream>>>(x, bo, x2);
  gemm32_k<5><<<dim3(M/128, DD/128, 2), 256, 0, stream>>>(ao, wto, nullptr, nullptr, x2,
                                                          M, DD, 512, DD, DD);

  // LN2
  ln_k<<<M, 256, 0, stream>>>(x2, g2, b2, h2);

  // FFN1 (T4 counted-vmcnt, GELU)
  gemm32_k<1><<<dim3(M/128, DFFN/128), 256, 0, stream>>>(h2, wtf1, bf1, nullptr, ff, M, DFFN, DD, DD, DD);

  // FFN2: out = x2 + bf2, then split-K2 atomic accumulate
  resadd_k<<<2048, 256, 0, stream>>>(x2, bf2, (float*)d_out);
  gemm32_k<5><<<dim3(M/128, DD/128, 2), 256, 0, stream>>>(ff, wtf2, nullptr, nullptr, (float*)d_out,
                                                          M, DD, 2048, DFFN, DFFN);
}

// Round 19
// 280.723 us; speedup vs baseline: 1.0246x; 1.0246x over previous
//
#include <hip/hip_runtime.h>
#include <hip/hip_bf16.h>
#include <math.h>

#define TT 1024
#define DD 1024
#define HH 16
#define KVHN 4
#define HDW 64
#define DFFN 4096
#define WIN 256

typedef __attribute__((ext_vector_type(4))) float f32x4;
typedef __attribute__((ext_vector_type(8))) __bf16 bf16x8;

typedef const __attribute__((address_space(1))) void gas_t;
typedef __attribute__((address_space(3))) void las_t;

__device__ inline unsigned short f2bf(float f){
  union { float f; unsigned u; } x; x.f = f;
  unsigned r = x.u + 0x7fffu + ((x.u >> 16) & 1u);
  return (unsigned short)(r >> 16);
}
__device__ inline float bf2f(unsigned short b){
  union { unsigned u; float f; } x; x.u = ((unsigned)b) << 16; return x.f;
}
__device__ inline f32x4 MFMA(bf16x8 a, bf16x8 b, f32x4 c){
  return __builtin_amdgcn_mfma_f32_16x16x32_bf16(a, b, c, 0, 0, 0);
}

__global__ void zero_k(float* out, int n){
  for (int i = blockIdx.x * blockDim.x + threadIdx.x; i < n; i += gridDim.x * blockDim.x)
    out[i] = 0.f;
}

// ---------- weight transpose: W[K][N] fp32 -> Wt[N][K] bf16 ----------
__global__ __launch_bounds__(256) void wtrans_k(const float* __restrict__ W,
                                                unsigned short* __restrict__ Wt,
                                                int K, int N){
  __shared__ float t[32][33];
  int n0 = blockIdx.x * 32, k0 = blockIdx.y * 32;
  int tx = threadIdx.x & 31, ty = threadIdx.x >> 5;
#pragma unroll
  for (int i = 0; i < 4; i++){
    int kk = ty * 4 + i;
    t[kk][tx] = W[(size_t)(k0 + kk) * N + n0 + tx];
  }
  __syncthreads();
#pragma unroll
  for (int i = 0; i < 4; i++){
    int nn = ty * 4 + i;
    Wt[(size_t)(n0 + nn) * K + k0 + tx] = f2bf(t[tx][nn]);
  }
}

// ---------- pack QKV bias ----------
__global__ void packb_k(const float* bq, const float* bk, const float* bv, float* o){
  int i = blockIdx.x * 256 + threadIdx.x;
  if (i < 1536)
    o[i] = (i < 1024) ? bq[i] : ((i < 1280) ? bk[i - 1024] : bv[i - 1280]);
}

// ---------- layernorm fp32 row -> bf16 row; optionally also resout = x + rbias ----------
template<int RES>
__global__ __launch_bounds__(256) void ln_k(const float* __restrict__ x,
                                            const float* __restrict__ g,
                                            const float* __restrict__ b,
                                            unsigned short* __restrict__ out,
                                            const float* __restrict__ rbias,
                                            float* __restrict__ resout){
  __shared__ float red[4];
  int row = blockIdx.x, tid = threadIdx.x;
  const float* xr = x + (size_t)row * DD;
  float4 v = *(const float4*)(xr + tid * 4);
  if constexpr (RES){
    float4 rb = *(const float4*)(rbias + tid * 4);
    float4 ov2;
    ov2.x = v.x + rb.x; ov2.y = v.y + rb.y; ov2.z = v.z + rb.z; ov2.w = v.w + rb.w;
    *(float4*)(resout + (size_t)row * DD + tid * 4) = ov2;
  }
  float s = v.x + v.y + v.z + v.w;
#pragma unroll
  for (int off = 32; off; off >>= 1) s += __shfl_xor(s, off);
  if ((tid & 63) == 0) red[tid >> 6] = s;
  __syncthreads();
  float mu = (red[0] + red[1] + red[2] + red[3]) * (1.f / DD);
  __syncthreads();
  float dx = v.x - mu, dy = v.y - mu, dz = v.z - mu, dw = v.w - mu;
  float sq = dx*dx + dy*dy + dz*dz + dw*dw;
#pragma unroll
  for (int off = 32; off; off >>= 1) sq += __shfl_xor(sq, off);
  if ((tid & 63) == 0) red[tid >> 6] = sq;
  __syncthreads();
  float var = (red[0] + red[1] + red[2] + red[3]) * (1.f / DD);
  float inv = rsqrtf(var + 1e-5f);
  float4 gv = *(const float4*)(g + tid * 4);
  float4 bv = *(const float4*)(b + tid * 4);
  unsigned short* orow = out + (size_t)row * DD + tid * 4;
  orow[0] = f2bf(dx * inv * gv.x + bv.x);
  orow[1] = f2bf(dy * inv * gv.y + bv.y);
  orow[2] = f2bf(dz * inv * gv.z + bv.z);
  orow[3] = f2bf(dw * inv * gv.w + bv.w);
}

// ---------- 128x128 BK=32 dbuf GEMM (r17-proven): 32KB LDS, ~3.5 blocks/CU ----------
// 2-phase: issue next tile's 4 gload_lds, ds_read+16 MFMA, one __syncthreads.
// Conflict-free swizzle: chunk c of row R at pos c ^ ((R>>1)&3).
// EPI 0: bf16. 1: GELU bf16. 2: +res fp32. 5: unsafeAtomicAdd fp32 (no bias).
template<int EPI>
__global__ __launch_bounds__(256, 4) void gemm32_k(const unsigned short* __restrict__ A,
                                                   const unsigned short* __restrict__ Bt,
                                                   const float* __restrict__ bias,
                                                   const float* __restrict__ res,
                                                   void* __restrict__ Cout,
                                                   int M, int N, int Klen, int lda, int ldb){
  __shared__ unsigned short As[2][4096];
  __shared__ unsigned short Bs[2][4096];
  int tid = threadIdx.x;
  int row0 = blockIdx.x * 128, col0 = blockIdx.y * 128;
  A  += (size_t)blockIdx.z * Klen;
  Bt += (size_t)blockIdx.z * Klen;
  int wid = tid >> 6, lane = tid & 63;
  int wm = (wid >> 1) * 64, wn = (wid & 1) * 64;
  int lr = lane & 15, lg = lane >> 4;
  f32x4 acc[4][4] = {};

  int srow = tid >> 2;                               // 0..63
  int scol = ((tid & 3) ^ ((srow >> 1) & 3)) * 8;    // pre-swizzled source chunk
  const unsigned short* gA0 = A  + (size_t)(row0 + srow) * lda + scol;
  const unsigned short* gB0 = Bt + (size_t)(col0 + srow) * ldb + scol;
  int lbase = wid * 512;                             // ushorts

  int NT = Klen >> 5;
#pragma unroll
  for (int j = 0; j < 2; j++){
    __builtin_amdgcn_global_load_lds((gas_t*)(gA0 + (size_t)(j*64)*lda), (las_t*)&As[0][j*2048 + lbase], 16, 0, 0);
    __builtin_amdgcn_global_load_lds((gas_t*)(gB0 + (size_t)(j*64)*ldb), (las_t*)&Bs[0][j*2048 + lbase], 16, 0, 0);
  }
  __syncthreads();
  int cur = 0;
  for (int t = 0; t < NT; t++){
    if (t + 1 < NT){
      int k0 = (t + 1) << 5;
      int nb = cur ^ 1;
#pragma unroll
      for (int j = 0; j < 2; j++){
        __builtin_amdgcn_global_load_lds((gas_t*)(gA0 + (size_t)(j*64)*lda + k0), (las_t*)&As[nb][j*2048 + lbase], 16, 0, 0);
        __builtin_amdgcn_global_load_lds((gas_t*)(gB0 + (size_t)(j*64)*ldb + k0), (las_t*)&Bs[nb][j*2048 + lbase], 16, 0, 0);
      }
    }
    bf16x8 af[4], bf[4];
#pragma unroll
    for (int mt = 0; mt < 4; mt++){
      int R = wm + mt*16 + lr;
      af[mt] = *(const bf16x8*)&As[cur][R * 32 + ((lg ^ ((R >> 1) & 3)) << 3)];
    }
#pragma unroll
    for (int nt2 = 0; nt2 < 4; nt2++){
      int R = wn + nt2*16 + lr;
      bf[nt2] = *(const bf16x8*)&Bs[cur][R * 32 + ((lg ^ ((R >> 1) & 3)) << 3)];
    }
#pragma unroll
    for (int mt = 0; mt < 4; mt++)
#pragma unroll
      for (int nt2 = 0; nt2 < 4; nt2++)
        acc[mt][nt2] = MFMA(af[mt], bf[nt2], acc[mt][nt2]);
    __syncthreads();
    cur ^= 1;
  }
#pragma unroll
  for (int mt = 0; mt < 4; mt++){
#pragma unroll
    for (int r = 0; r < 4; r++){
      int gr = row0 + wm + mt*16 + lg*4 + r;
#pragma unroll
      for (int nt2 = 0; nt2 < 4; nt2++){
        int gc = col0 + wn + nt2*16 + lr;
        if constexpr (EPI == 5){
          unsafeAtomicAdd(&((float*)Cout)[(size_t)gr * N + gc], acc[mt][nt2][r]);
        } else {
          float val = acc[mt][nt2][r] + bias[gc];
          if constexpr (EPI == 1){
            val = 0.5f * val * (1.f + erff(val * 0.70710678118f));
          }
          if constexpr (EPI == 2){
            float ov = val + res[(size_t)gr * N + gc];
            ((float*)Cout)[(size_t)gr * N + gc] = ov;
          } else {
            ((unsigned short*)Cout)[(size_t)gr * N + gc] = f2bf(val);
          }
        }
      }
    }
  }
}

// ---------- RoPE in-place, NEGATED rotation (verified r8), strided rows ----------
template<int NH>
__global__ __launch_bounds__(256) void rope_k(unsigned short* base, int rs){
  int idx = blockIdx.x * 8 + (threadIdx.x >> 5);
  int d = threadIdx.x & 31;
  int row = idx / NH;          // b*T + t
  int head = idx % NH;
  int t = row & (TT - 1);
  unsigned short* p = base + (size_t)row * rs + head * HDW;
  float x1 = bf2f(p[d]);
  float x2 = bf2f(p[d + 32]);
  float theta = powf(10000.f, -(float)d * (1.f / 32.f));
  float c, s;
  sincosf((float)t * theta, &c, &s);
  p[d]      = f2bf(x1 * c + x2 * s);
  p[d + 32] = f2bf(x2 * c - x1 * s);
}

// ---------- V transpose: packed v rows (stride rs) -> vt[b][kvh][d][t] ----------
__global__ __launch_bounds__(256) void vtrans_k(const unsigned short* __restrict__ v, int rs,
                                                unsigned short* __restrict__ vt){
  __shared__ unsigned short tile[64][72];
  int t0 = blockIdx.x * 64;
  int kvh = blockIdx.y, b = blockIdx.z;
  int i = threadIdx.x;
  int tl = i >> 2, dc = (i & 3) * 16;
  const unsigned short* src = v + (size_t)(b * TT + t0 + tl) * rs + kvh * HDW + dc;
  *(uint4*)&tile[tl][dc]     = *(const uint4*)src;
  *(uint4*)&tile[tl][dc + 8] = *(const uint4*)(src + 8);
  __syncthreads();
  int d = i >> 2, tc = (i & 3) * 16;
  unsigned short tmp[16];
#pragma unroll
  for (int e = 0; e < 16; e++) tmp[e] = tile[tc + e][d];
  unsigned short* dst = vt + ((size_t)((b * KVHN + kvh) * HDW) + d) * TT + t0 + tc;
  *(uint4*)dst       = *(uint4*)tmp;
  *(uint4*)(dst + 8) = *(uint4*)(tmp + 8);
}

// ---------- flash attention, 1 wave per (b, h, 32-row q-tile); strided q/k ----------
__global__ __launch_bounds__(64) void attn_k(const unsigned short* __restrict__ q, int qrs,
                                             const unsigned short* __restrict__ k, int krs,
                                             const unsigned short* __restrict__ vt,
                                             unsigned short* __restrict__ o){
  __shared__ unsigned short P[32 * 40];
  __shared__ float sc_l[32];
  int qt = blockIdx.x, h = blockIdx.y, b = blockIdx.z;
  int kvh = h >> 2;
  int lane = threadIdx.x;
  int lr = lane & 15, lg = lane >> 4;
  int q0 = qt * 32;
  bf16x8 qf[2][2];
#pragma unroll
  for (int qi = 0; qi < 2; qi++)
#pragma unroll
    for (int ks = 0; ks < 2; ks++)
      qf[qi][ks] = *(const bf16x8*)(q + (size_t)(b*TT + q0 + qi*16 + lr) * qrs + h * HDW + ks*32 + lg*8);
  f32x4 oa[2][4] = {};
  float m_st[2] = {-1e30f, -1e30f};
  float l_st[2] = {0.f, 0.f};
  int kt_lo = (q0 - (WIN - 1)) > 0 ? ((q0 - (WIN - 1)) >> 5) : 0;
  int kt_hi = (q0 + 31) >> 5;
  for (int kt = kt_lo; kt <= kt_hi; kt++){
    int kb = kt * 32;
    bf16x8 kf[2][2];
#pragma unroll
    for (int ki = 0; ki < 2; ki++)
#pragma unroll
      for (int ks = 0; ks < 2; ks++)
        kf[ki][ks] = *(const bf16x8*)(k + (size_t)(b*TT + kb + ki*16 + lr) * krs + kvh * HDW + ks*32 + lg*8);
    f32x4 s[2][2] = {};
#pragma unroll
    for (int ki = 0; ki < 2; ki++)
#pragma unroll
      for (int qi = 0; qi < 2; qi++){
        s[ki][qi] = MFMA(kf[ki][0], qf[qi][0], s[ki][qi]);
        s[ki][qi] = MFMA(kf[ki][1], qf[qi][1], s[ki][qi]);
      }
#pragma unroll
    for (int qi = 0; qi < 2; qi++){
      int qa = q0 + qi*16 + lr;
      float pv[8];
      float mx = -1e30f;
#pragma unroll
      for (int ki = 0; ki < 2; ki++)
#pragma unroll
        for (int r = 0; r < 4; r++){
          int ka = kb + ki*16 + lg*4 + r;
          float val = s[ki][qi][r] * 0.125f;
          bool ok = (ka <= qa) && (qa - ka < WIN);
          val = ok ? val : -1e9f;
          pv[ki*4 + r] = val;
          mx = fmaxf(mx, val);
        }
      mx = fmaxf(mx, __shfl_xor(mx, 16));
      mx = fmaxf(mx, __shfl_xor(mx, 32));
      float mn = fmaxf(m_st[qi], mx);
      float scl = __expf(m_st[qi] - mn);
      m_st[qi] = mn;
      float ls = 0.f;
#pragma unroll
      for (int j = 0; j < 8; j++){ float p = __expf(pv[j] - mn); pv[j] = p; ls += p; }
      ls += __shfl_xor(ls, 16);
      ls += __shfl_xor(ls, 32);
      l_st[qi] = l_st[qi] * scl + ls;
#pragma unroll
      for (int ki = 0; ki < 2; ki++){
        uint2 w;
        w.x = (unsigned)f2bf(pv[ki*4+0]) | ((unsigned)f2bf(pv[ki*4+1]) << 16);
        w.y = (unsigned)f2bf(pv[ki*4+2]) | ((unsigned)f2bf(pv[ki*4+3]) << 16);
        *(uint2*)&P[(qi*16 + lr) * 40 + ki*16 + lg*4] = w;
      }
      if (lg == 0) sc_l[qi*16 + lr] = scl;
    }
    __syncthreads();
#pragma unroll
    for (int qi = 0; qi < 2; qi++)
#pragma unroll
      for (int r = 0; r < 4; r++){
        float f = sc_l[qi*16 + lg*4 + r];
#pragma unroll
        for (int di = 0; di < 4; di++) oa[qi][di][r] *= f;
      }
    bf16x8 pa[2];
#pragma unroll
    for (int qi = 0; qi < 2; qi++)
      pa[qi] = *(const bf16x8*)&P[(qi*16 + lr) * 40 + lg*8];
#pragma unroll
    for (int di = 0; di < 4; di++){
      bf16x8 vb = *(const bf16x8*)(vt + ((size_t)((b*KVHN + kvh) * HDW) + di*16 + lr) * TT + kb + lg*8);
#pragma unroll
      for (int qi = 0; qi < 2; qi++)
        oa[qi][di] = MFMA(pa[qi], vb, oa[qi][di]);
    }
    __syncthreads();
  }
  if (lg == 0){ sc_l[lr] = l_st[0]; sc_l[16 + lr] = l_st[1]; }
  __syncthreads();
#pragma unroll
  for (int qi = 0; qi < 2; qi++)
#pragma unroll
    for (int r = 0; r < 4; r++){
      float inv = 1.f / sc_l[qi*16 + lg*4 + r];
      int t = q0 + qi*16 + lg*4 + r;
#pragma unroll
      for (int di = 0; di < 4; di++)
        o[((size_t)((b*TT + t) * HH) + h) * HDW + di*16 + lr] = f2bf(oa[qi][di][r] * inv);
    }
}

extern "C" void kernel_launch(void* const* d_in, const int* in_sizes, int n_in,
                              void* d_out, int out_size, void* d_ws, size_t ws_size,
                              hipStream_t stream){
  const float* x   = (const float*)d_in[0];
  const float* Wq  = (const float*)d_in[1];
  const float* bq  = (const float*)d_in[2];
  const float* Wk  = (const float*)d_in[3];
  const float* bk  = (const float*)d_in[4];
  const float* Wv  = (const float*)d_in[5];
  const float* bv  = (const float*)d_in[6];
  const float* Wo  = (const float*)d_in[7];
  const float* bo  = (const float*)d_in[8];
  const float* g1  = (const float*)d_in[9];
  const float* b1  = (const float*)d_in[10];
  const float* Wf1 = (const float*)d_in[11];
  const float* bf1 = (const float*)d_in[12];
  const float* Wf2 = (const float*)d_in[13];
  const float* bf2 = (const float*)d_in[14];
  const float* g2  = (const float*)d_in[15];
  const float* b2  = (const float*)d_in[16];

  static const int want[17] = {4194304, 1048576, 1024, 262144, 256, 262144, 256,
                               1048576, 1024, 1024, 1024, 4194304, 4096, 4194304,
                               1024, 1024, 1024};
  bool bad = (n_in != 17) || (out_size != 4194304);
  if (!bad) for (int i = 0; i < 17; i++) if (in_sizes[i] != want[i]) bad = true;
  if (bad){
    zero_k<<<2048, 256, 0, stream>>>((float*)d_out, out_size);
    return;
  }

  const int M = 4 * TT;       // 4096 rows
  const int QKVN = 1536;      // packed q|k|v width
  char* ws = (char*)d_ws;
  size_t off = 0;
  auto alloc = [&](size_t bytes) -> void* {
    void* p = ws + off; off += (bytes + 255) & ~(size_t)255; return p;
  };
  unsigned short* wqkv = (unsigned short*)alloc((size_t)QKVN * DD * 2);
  unsigned short* wto  = (unsigned short*)alloc((size_t)DD * DD * 2);
  unsigned short* wtf1 = (unsigned short*)alloc((size_t)DFFN * DD * 2);
  unsigned short* wtf2 = (unsigned short*)alloc((size_t)DD * DFFN * 2);
  float*          bqkv = (float*)alloc((size_t)QKVN * 4);
  unsigned short* h1   = (unsigned short*)alloc((size_t)M * DD * 2);
  unsigned short* qkv  = (unsigned short*)alloc((size_t)M * QKVN * 2);
  unsigned short* vtb  = (unsigned short*)alloc((size_t)M * 256 * 2);
  unsigned short* ao   = (unsigned short*)alloc((size_t)M * DD * 2);
  float*          x2   = (float*)alloc((size_t)M * DD * 4);
  unsigned short* h2   = h1;            // reuse
  unsigned short* ff   = (unsigned short*)alloc((size_t)M * DFFN * 2);
  (void)ws_size;

  // weights -> bf16 transposed (QKV packed)
  wtrans_k<<<dim3(DD/32,  DD/32),  256, 0, stream>>>(Wq,  wqkv,                       DD,  DD);
  wtrans_k<<<dim3(256/32, DD/32),  256, 0, stream>>>(Wk,  wqkv + (size_t)1024 * DD,   DD,  256);
  wtrans_k<<<dim3(256/32, DD/32),  256, 0, stream>>>(Wv,  wqkv + (size_t)1280 * DD,   DD,  256);
  wtrans_k<<<dim3(DD/32,  DD/32),  256, 0, stream>>>(Wo,  wto,  DD,  DD);
  wtrans_k<<<dim3(DFFN/32,DD/32),  256, 0, stream>>>(Wf1, wtf1, DD,  DFFN);
  wtrans_k<<<dim3(DD/32,  DFFN/32),256, 0, stream>>>(Wf2, wtf2, DFFN,DD);
  packb_k<<<6, 256, 0, stream>>>(bq, bk, bv, bqkv);

  // LN1 (+ fused x2 = x + bo init for Wo split-K)
  ln_k<1><<<M, 256, 0, stream>>>(x, g1, b1, h1, bo, x2);

  // QKV fused (r17-proven 2-phase)
  gemm32_k<0><<<dim3(M/128, QKVN/128), 256, 0, stream>>>(h1, wqkv, bqkv, nullptr, qkv, M, QKVN, DD, DD, DD);

  // RoPE on packed buffer
  rope_k<HH>  <<<(M * HH) / 8,   256, 0, stream>>>(qkv,        QKVN);
  rope_k<KVHN><<<(M * KVHN) / 8, 256, 0, stream>>>(qkv + 1024, QKVN);

  // V transpose
  vtrans_k<<<dim3(TT/64, KVHN, 4), 256, 0, stream>>>(qkv + 1280, QKVN, vtb);

  // attention
  attn_k<<<dim3(TT/32, HH, 4), 64, 0, stream>>>(qkv, QKVN, qkv + 1024, QKVN, vtb, ao);

  // Wo: split-K2 atomic accumulate onto x2 (= x + bo from LN1)
  gemm32_k<5><<<dim3(M/128, DD/128, 2), 256, 0, stream>>>(ao, wto, nullptr, nullptr, x2,
                                                          M, DD, 512, DD, DD);

  // LN2 (+ fused d_out = x2 + bf2 init for FFN2 split-K)
  ln_k<1><<<M, 256, 0, stream>>>(x2, g2, b2, h2, bf2, (float*)d_out);

  // FFN1 (r17-proven 2-phase, GELU)
  gemm32_k<1><<<dim3(M/128, DFFN/128), 256, 0, stream>>>(h2, wtf1, bf1, nullptr, ff, M, DFFN, DD, DD, DD);

  // FFN2: split-K4 atomic accumulate onto d_out (= x2 + bf2 from LN2)
  gemm32_k<5><<<dim3(M/128, DD/128, 4), 256, 0, stream>>>(ff, wtf2, nullptr, nullptr, (float*)d_out,
                                                          M, DD, 1024, DFFN, DFFN);
}

// Round 20
// 254.542 us; speedup vs baseline: 1.1299x; 1.1029x over previous
//
#include <hip/hip_runtime.h>
#include <hip/hip_bf16.h>
#include <math.h>

#define TT 1024
#define DD 1024
#define HH 16
#define KVHN 4
#define HDW 64
#define DFFN 4096
#define WIN 256

typedef __attribute__((ext_vector_type(4))) float f32x4;
typedef __attribute__((ext_vector_type(8))) __bf16 bf16x8;

typedef const __attribute__((address_space(1))) void gas_t;
typedef __attribute__((address_space(3))) void las_t;

__device__ inline unsigned short f2bf(float f){
  union { float f; unsigned u; } x; x.f = f;
  unsigned r = x.u + 0x7fffu + ((x.u >> 16) & 1u);
  return (unsigned short)(r >> 16);
}
__device__ inline float bf2f(unsigned short b){
  union { unsigned u; float f; } x; x.u = ((unsigned)b) << 16; return x.f;
}
__device__ inline f32x4 MFMA(bf16x8 a, bf16x8 b, f32x4 c){
  return __builtin_amdgcn_mfma_f32_16x16x32_bf16(a, b, c, 0, 0, 0);
}

__global__ void zero_k(float* out, int n){
  for (int i = blockIdx.x * blockDim.x + threadIdx.x; i < n; i += gridDim.x * blockDim.x)
    out[i] = 0.f;
}

// ---------- ALL weight transposes in one launch ----------
// W[K][N] fp32 -> Wt[N][K] bf16, 32x32 tiles; segment dispatch by blockIdx.x.
// tiles: Wq 1024 | Wk 256 | Wv 256 | Wo 1024 | Wf1 4096 | Wf2 4096  (total 10752)
__global__ __launch_bounds__(256) void wtransall_k(const float* __restrict__ Wq,
                                                   const float* __restrict__ Wk,
                                                   const float* __restrict__ Wv,
                                                   const float* __restrict__ Wo,
                                                   const float* __restrict__ Wf1,
                                                   const float* __restrict__ Wf2,
                                                   unsigned short* __restrict__ wqkv,
                                                   unsigned short* __restrict__ wto,
                                                   unsigned short* __restrict__ wtf1,
                                                   unsigned short* __restrict__ wtf2){
  int bid = blockIdx.x;
  const float* W; unsigned short* Wt; int K, N;
  if (bid < 1024)      { W = Wq;  Wt = wqkv;                     K = 1024; N = 1024; }
  else if (bid < 1280) { W = Wk;  Wt = wqkv + (size_t)1024*DD;   K = 1024; N = 256;  bid -= 1024; }
  else if (bid < 1536) { W = Wv;  Wt = wqkv + (size_t)1280*DD;   K = 1024; N = 256;  bid -= 1280; }
  else if (bid < 2560) { W = Wo;  Wt = wto;                      K = 1024; N = 1024; bid -= 1536; }
  else if (bid < 6656) { W = Wf1; Wt = wtf1;                     K = 1024; N = 4096; bid -= 2560; }
  else                 { W = Wf2; Wt = wtf2;                     K = 4096; N = 1024; bid -= 6656; }
  int nt = N >> 5;
  int n0 = (bid % nt) * 32, k0 = (bid / nt) * 32;
  __shared__ float t[32][33];
  int tx = threadIdx.x & 31, ty = threadIdx.x >> 5;
#pragma unroll
  for (int i = 0; i < 4; i++){
    int kk = ty * 4 + i;
    t[kk][tx] = W[(size_t)(k0 + kk) * N + n0 + tx];
  }
  __syncthreads();
#pragma unroll
  for (int i = 0; i < 4; i++){
    int nn = ty * 4 + i;
    Wt[(size_t)(n0 + nn) * K + k0 + tx] = f2bf(t[tx][nn]);
  }
}

// ---------- pack QKV bias ----------
__global__ void packb_k(const float* bq, const float* bk, const float* bv, float* o){
  int i = blockIdx.x * 256 + threadIdx.x;
  if (i < 1536)
    o[i] = (i < 1024) ? bq[i] : ((i < 1280) ? bk[i - 1024] : bv[i - 1280]);
}

// ---------- layernorm fp32 row -> bf16 row; optionally also resout = x + rbias ----------
template<int RES>
__global__ __launch_bounds__(256) void ln_k(const float* __restrict__ x,
                                            const float* __restrict__ g,
                                            const float* __restrict__ b,
                                            unsigned short* __restrict__ out,
                                            const float* __restrict__ rbias,
                                            float* __restrict__ resout){
  __shared__ float red[4];
  int row = blockIdx.x, tid = threadIdx.x;
  const float* xr = x + (size_t)row * DD;
  float4 v = *(const float4*)(xr + tid * 4);
  if constexpr (RES){
    float4 rb = *(const float4*)(rbias + tid * 4);
    float4 ov2;
    ov2.x = v.x + rb.x; ov2.y = v.y + rb.y; ov2.z = v.z + rb.z; ov2.w = v.w + rb.w;
    *(float4*)(resout + (size_t)row * DD + tid * 4) = ov2;
  }
  float s = v.x + v.y + v.z + v.w;
#pragma unroll
  for (int off = 32; off; off >>= 1) s += __shfl_xor(s, off);
  if ((tid & 63) == 0) red[tid >> 6] = s;
  __syncthreads();
  float mu = (red[0] + red[1] + red[2] + red[3]) * (1.f / DD);
  __syncthreads();
  float dx = v.x - mu, dy = v.y - mu, dz = v.z - mu, dw = v.w - mu;
  float sq = dx*dx + dy*dy + dz*dz + dw*dw;
#pragma unroll
  for (int off = 32; off; off >>= 1) sq += __shfl_xor(sq, off);
  if ((tid & 63) == 0) red[tid >> 6] = sq;
  __syncthreads();
  float var = (red[0] + red[1] + red[2] + red[3]) * (1.f / DD);
  float inv = rsqrtf(var + 1e-5f);
  float4 gv = *(const float4*)(g + tid * 4);
  float4 bv = *(const float4*)(b + tid * 4);
  unsigned short* orow = out + (size_t)row * DD + tid * 4;
  orow[0] = f2bf(dx * inv * gv.x + bv.x);
  orow[1] = f2bf(dy * inv * gv.y + bv.y);
  orow[2] = f2bf(dz * inv * gv.z + bv.z);
  orow[3] = f2bf(dw * inv * gv.w + bv.w);
}

// ---------- 128x128 BK=32 dbuf GEMM (r17-proven): 32KB LDS, ~3.5 blocks/CU ----------
// 2-phase: issue next tile's 4 gload_lds, ds_read+16 MFMA, one __syncthreads.
// Conflict-free swizzle: chunk c of row R at pos c ^ ((R>>1)&3).
// EPI 0: bf16. 1: GELU bf16. 2: +res fp32. 5: unsafeAtomicAdd fp32 (no bias).
template<int EPI>
__global__ __launch_bounds__(256, 4) void gemm32_k(const unsigned short* __restrict__ A,
                                                   const unsigned short* __restrict__ Bt,
                                                   const float* __restrict__ bias,
                                                   const float* __restrict__ res,
                                                   void* __restrict__ Cout,
                                                   int M, int N, int Klen, int lda, int ldb){
  __shared__ unsigned short As[2][4096];
  __shared__ unsigned short Bs[2][4096];
  int tid = threadIdx.x;
  int row0 = blockIdx.x * 128, col0 = blockIdx.y * 128;
  A  += (size_t)blockIdx.z * Klen;
  Bt += (size_t)blockIdx.z * Klen;
  int wid = tid >> 6, lane = tid & 63;
  int wm = (wid >> 1) * 64, wn = (wid & 1) * 64;
  int lr = lane & 15, lg = lane >> 4;
  f32x4 acc[4][4] = {};

  int srow = tid >> 2;                               // 0..63
  int scol = ((tid & 3) ^ ((srow >> 1) & 3)) * 8;    // pre-swizzled source chunk
  const unsigned short* gA0 = A  + (size_t)(row0 + srow) * lda + scol;
  const unsigned short* gB0 = Bt + (size_t)(col0 + srow) * ldb + scol;
  int lbase = wid * 512;                             // ushorts

  int NT = Klen >> 5;
#pragma unroll
  for (int j = 0; j < 2; j++){
    __builtin_amdgcn_global_load_lds((gas_t*)(gA0 + (size_t)(j*64)*lda), (las_t*)&As[0][j*2048 + lbase], 16, 0, 0);
    __builtin_amdgcn_global_load_lds((gas_t*)(gB0 + (size_t)(j*64)*ldb), (las_t*)&Bs[0][j*2048 + lbase], 16, 0, 0);
  }
  __syncthreads();
  int cur = 0;
  for (int t = 0; t < NT; t++){
    if (t + 1 < NT){
      int k0 = (t + 1) << 5;
      int nb = cur ^ 1;
#pragma unroll
      for (int j = 0; j < 2; j++){
        __builtin_amdgcn_global_load_lds((gas_t*)(gA0 + (size_t)(j*64)*lda + k0), (las_t*)&As[nb][j*2048 + lbase], 16, 0, 0);
        __builtin_amdgcn_global_load_lds((gas_t*)(gB0 + (size_t)(j*64)*ldb + k0), (las_t*)&Bs[nb][j*2048 + lbase], 16, 0, 0);
      }
    }
    bf16x8 af[4], bf[4];
#pragma unroll
    for (int mt = 0; mt < 4; mt++){
      int R = wm + mt*16 + lr;
      af[mt] = *(const bf16x8*)&As[cur][R * 32 + ((lg ^ ((R >> 1) & 3)) << 3)];
    }
#pragma unroll
    for (int nt2 = 0; nt2 < 4; nt2++){
      int R = wn + nt2*16 + lr;
      bf[nt2] = *(const bf16x8*)&Bs[cur][R * 32 + ((lg ^ ((R >> 1) & 3)) << 3)];
    }
#pragma unroll
    for (int mt = 0; mt < 4; mt++)
#pragma unroll
      for (int nt2 = 0; nt2 < 4; nt2++)
        acc[mt][nt2] = MFMA(af[mt], bf[nt2], acc[mt][nt2]);
    __syncthreads();
    cur ^= 1;
  }
#pragma unroll
  for (int mt = 0; mt < 4; mt++){
#pragma unroll
    for (int r = 0; r < 4; r++){
      int gr = row0 + wm + mt*16 + lg*4 + r;
#pragma unroll
      for (int nt2 = 0; nt2 < 4; nt2++){
        int gc = col0 + wn + nt2*16 + lr;
        if constexpr (EPI == 5){
          unsafeAtomicAdd(&((float*)Cout)[(size_t)gr * N + gc], acc[mt][nt2][r]);
        } else {
          float val = acc[mt][nt2][r] + bias[gc];
          if constexpr (EPI == 1){
            val = 0.5f * val * (1.f + erff(val * 0.70710678118f));
          }
          if constexpr (EPI == 2){
            float ov = val + res[(size_t)gr * N + gc];
            ((float*)Cout)[(size_t)gr * N + gc] = ov;
          } else {
            ((unsigned short*)Cout)[(size_t)gr * N + gc] = f2bf(val);
          }
        }
      }
    }
  }
}

// ---------- RoPE in-place, NEGATED rotation (verified r8), strided rows ----------
template<int NH>
__global__ __launch_bounds__(256) void rope_k(unsigned short* base, int rs){
  int idx = blockIdx.x * 8 + (threadIdx.x >> 5);
  int d = threadIdx.x & 31;
  int row = idx / NH;          // b*T + t
  int head = idx % NH;
  int t = row & (TT - 1);
  unsigned short* p = base + (size_t)row * rs + head * HDW;
  float x1 = bf2f(p[d]);
  float x2 = bf2f(p[d + 32]);
  float theta = powf(10000.f, -(float)d * (1.f / 32.f));
  float c, s;
  sincosf((float)t * theta, &c, &s);
  p[d]      = f2bf(x1 * c + x2 * s);
  p[d + 32] = f2bf(x2 * c - x1 * s);
}

// ---------- V transpose: packed v rows (stride rs) -> vt[b][kvh][d][t] ----------
__global__ __launch_bounds__(256) void vtrans_k(const unsigned short* __restrict__ v, int rs,
                                                unsigned short* __restrict__ vt){
  __shared__ unsigned short tile[64][72];
  int t0 = blockIdx.x * 64;
  int kvh = blockIdx.y, b = blockIdx.z;
  int i = threadIdx.x;
  int tl = i >> 2, dc = (i & 3) * 16;
  const unsigned short* src = v + (size_t)(b * TT + t0 + tl) * rs + kvh * HDW + dc;
  *(uint4*)&tile[tl][dc]     = *(const uint4*)src;
  *(uint4*)&tile[tl][dc + 8] = *(const uint4*)(src + 8);
  __syncthreads();
  int d = i >> 2, tc = (i & 3) * 16;
  unsigned short tmp[16];
#pragma unroll
  for (int e = 0; e < 16; e++) tmp[e] = tile[tc + e][d];
  unsigned short* dst = vt + ((size_t)((b * KVHN + kvh) * HDW) + d) * TT + t0 + tc;
  *(uint4*)dst       = *(uint4*)tmp;
  *(uint4*)(dst + 8) = *(uint4*)(tmp + 8);
}

// ---------- flash attention, 1 wave per (b, h, 32-row q-tile); strided q/k ----------
__global__ __launch_bounds__(64) void attn_k(const unsigned short* __restrict__ q, int qrs,
                                             const unsigned short* __restrict__ k, int krs,
                                             const unsigned short* __restrict__ vt,
                                             unsigned short* __restrict__ o){
  __shared__ unsigned short P[32 * 40];
  __shared__ float sc_l[32];
  int qt = blockIdx.x, h = blockIdx.y, b = blockIdx.z;
  int kvh = h >> 2;
  int lane = threadIdx.x;
  int lr = lane & 15, lg = lane >> 4;
  int q0 = qt * 32;
  bf16x8 qf[2][2];
#pragma unroll
  for (int qi = 0; qi < 2; qi++)
#pragma unroll
    for (int ks = 0; ks < 2; ks++)
      qf[qi][ks] = *(const bf16x8*)(q + (size_t)(b*TT + q0 + qi*16 + lr) * qrs + h * HDW + ks*32 + lg*8);
  f32x4 oa[2][4] = {};
  float m_st[2] = {-1e30f, -1e30f};
  float l_st[2] = {0.f, 0.f};
  int kt_lo = (q0 - (WIN - 1)) > 0 ? ((q0 - (WIN - 1)) >> 5) : 0;
  int kt_hi = (q0 + 31) >> 5;
  for (int kt = kt_lo; kt <= kt_hi; kt++){
    int kb = kt * 32;
    bf16x8 kf[2][2];
#pragma unroll
    for (int ki = 0; ki < 2; ki++)
#pragma unroll
      for (int ks = 0; ks < 2; ks++)
        kf[ki][ks] = *(const bf16x8*)(k + (size_t)(b*TT + kb + ki*16 + lr) * krs + kvh * HDW + ks*32 + lg*8);
    f32x4 s[2][2] = {};
#pragma unroll
    for (int ki = 0; ki < 2; ki++)
#pragma unroll
      for (int qi = 0; qi < 2; qi++){
        s[ki][qi] = MFMA(kf[ki][0], qf[qi][0], s[ki][qi]);
        s[ki][qi] = MFMA(kf[ki][1], qf[qi][1], s[ki][qi]);
      }
#pragma unroll
    for (int qi = 0; qi < 2; qi++){
      int qa = q0 + qi*16 + lr;
      float pv[8];
      float mx = -1e30f;
#pragma unroll
      for (int ki = 0; ki < 2; ki++)
#pragma unroll
        for (int r = 0; r < 4; r++){
          int ka = kb + ki*16 + lg*4 + r;
          float val = s[ki][qi][r] * 0.125f;
          bool ok = (ka <= qa) && (qa - ka < WIN);
          val = ok ? val : -1e9f;
          pv[ki*4 + r] = val;
          mx = fmaxf(mx, val);
        }
      mx = fmaxf(mx, __shfl_xor(mx, 16));
      mx = fmaxf(mx, __shfl_xor(mx, 32));
      float mn = fmaxf(m_st[qi], mx);
      float scl = __expf(m_st[qi] - mn);
      m_st[qi] = mn;
      float ls = 0.f;
#pragma unroll
      for (int j = 0; j < 8; j++){ float p = __expf(pv[j] - mn); pv[j] = p; ls += p; }
      ls += __shfl_xor(ls, 16);
      ls += __shfl_xor(ls, 32);
      l_st[qi] = l_st[qi] * scl + ls;
#pragma unroll
      for (int ki = 0; ki < 2; ki++){
        uint2 w;
        w.x = (unsigned)f2bf(pv[ki*4+0]) | ((unsigned)f2bf(pv[ki*4+1]) << 16);
        w.y = (unsigned)f2bf(pv[ki*4+2]) | ((unsigned)f2bf(pv[ki*4+3]) << 16);
        *(uint2*)&P[(qi*16 + lr) * 40 + ki*16 + lg*4] = w;
      }
      if (lg == 0) sc_l[qi*16 + lr] = scl;
    }
    __syncthreads();
#pragma unroll
    for (int qi = 0; qi < 2; qi++)
#pragma unroll
      for (int r = 0; r < 4; r++){
        float f = sc_l[qi*16 + lg*4 + r];
#pragma unroll
        for (int di = 0; di < 4; di++) oa[qi][di][r] *= f;
      }
    bf16x8 pa[2];
#pragma unroll
    for (int qi = 0; qi < 2; qi++)
      pa[qi] = *(const bf16x8*)&P[(qi*16 + lr) * 40 + lg*8];
#pragma unroll
    for (int di = 0; di < 4; di++){
      bf16x8 vb = *(const bf16x8*)(vt + ((size_t)((b*KVHN + kvh) * HDW) + di*16 + lr) * TT + kb + lg*8);
#pragma unroll
      for (int qi = 0; qi < 2; qi++)
        oa[qi][di] = MFMA(pa[qi], vb, oa[qi][di]);
    }
    __syncthreads();
  }
  if (lg == 0){ sc_l[lr] = l_st[0]; sc_l[16 + lr] = l_st[1]; }
  __syncthreads();
#pragma unroll
  for (int qi = 0; qi < 2; qi++)
#pragma unroll
    for (int r = 0; r < 4; r++){
      float inv = 1.f / sc_l[qi*16 + lg*4 + r];
      int t = q0 + qi*16 + lg*4 + r;
#pragma unroll
      for (int di = 0; di < 4; di++)
        o[((size_t)((b*TT + t) * HH) + h) * HDW + di*16 + lr] = f2bf(oa[qi][di][r] * inv);
    }
}

extern "C" void kernel_launch(void* const* d_in, const int* in_sizes, int n_in,
                              void* d_out, int out_size, void* d_ws, size_t ws_size,
                              hipStream_t stream){
  const float* x   = (const float*)d_in[0];
  const float* Wq  = (const float*)d_in[1];
  const float* bq  = (const float*)d_in[2];
  const float* Wk  = (const float*)d_in[3];
  const float* bk  = (const float*)d_in[4];
  const float* Wv  = (const float*)d_in[5];
  const float* bv  = (const float*)d_in[6];
  const float* Wo  = (const float*)d_in[7];
  const float* bo  = (const float*)d_in[8];
  const float* g1  = (const float*)d_in[9];
  const float* b1  = (const float*)d_in[10];
  const float* Wf1 = (const float*)d_in[11];
  const float* bf1 = (const float*)d_in[12];
  const float* Wf2 = (const float*)d_in[13];
  const float* bf2 = (const float*)d_in[14];
  const float* g2  = (const float*)d_in[15];
  const float* b2  = (const float*)d_in[16];

  static const int want[17] = {4194304, 1048576, 1024, 262144, 256, 262144, 256,
                               1048576, 1024, 1024, 1024, 4194304, 4096, 4194304,
                               1024, 1024, 1024};
  bool bad = (n_in != 17) || (out_size != 4194304);
  if (!bad) for (int i = 0; i < 17; i++) if (in_sizes[i] != want[i]) bad = true;
  if (bad){
    zero_k<<<2048, 256, 0, stream>>>((float*)d_out, out_size);
    return;
  }

  const int M = 4 * TT;       // 4096 rows
  const int QKVN = 1536;      // packed q|k|v width
  char* ws = (char*)d_ws;
  size_t off = 0;
  auto alloc = [&](size_t bytes) -> void* {
    void* p = ws + off; off += (bytes + 255) & ~(size_t)255; return p;
  };
  unsigned short* wqkv = (unsigned short*)alloc((size_t)QKVN * DD * 2);
  unsigned short* wto  = (unsigned short*)alloc((size_t)DD * DD * 2);
  unsigned short* wtf1 = (unsigned short*)alloc((size_t)DFFN * DD * 2);
  unsigned short* wtf2 = (unsigned short*)alloc((size_t)DD * DFFN * 2);
  float*          bqkv = (float*)alloc((size_t)QKVN * 4);
  unsigned short* h1   = (unsigned short*)alloc((size_t)M * DD * 2);
  unsigned short* qkv  = (unsigned short*)alloc((size_t)M * QKVN * 2);
  unsigned short* vtb  = (unsigned short*)alloc((size_t)M * 256 * 2);
  unsigned short* ao   = (unsigned short*)alloc((size_t)M * DD * 2);
  float*          x2   = (float*)alloc((size_t)M * DD * 4);
  unsigned short* h2   = h1;            // reuse
  unsigned short* ff   = (unsigned short*)alloc((size_t)M * DFFN * 2);
  (void)ws_size;

  // all weight transposes in ONE launch (QKV packed)
  wtransall_k<<<10752, 256, 0, stream>>>(Wq, Wk, Wv, Wo, Wf1, Wf2, wqkv, wto, wtf1, wtf2);
  packb_k<<<6, 256, 0, stream>>>(bq, bk, bv, bqkv);

  // LN1 (+ fused x2 = x + bo init for Wo split-K)
  ln_k<1><<<M, 256, 0, stream>>>(x, g1, b1, h1, bo, x2);

  // QKV fused (r17-proven 2-phase)
  gemm32_k<0><<<dim3(M/128, QKVN/128), 256, 0, stream>>>(h1, wqkv, bqkv, nullptr, qkv, M, QKVN, DD, DD, DD);

  // RoPE on packed buffer
  rope_k<HH>  <<<(M * HH) / 8,   256, 0, stream>>>(qkv,        QKVN);
  rope_k<KVHN><<<(M * KVHN) / 8, 256, 0, stream>>>(qkv + 1024, QKVN);

  // V transpose
  vtrans_k<<<dim3(TT/64, KVHN, 4), 256, 0, stream>>>(qkv + 1280, QKVN, vtb);

  // attention
  attn_k<<<dim3(TT/32, HH, 4), 64, 0, stream>>>(qkv, QKVN, qkv + 1024, QKVN, vtb, ao);

  // Wo: split-K2 atomic accumulate onto x2 (= x + bo from LN1)
  gemm32_k<5><<<dim3(M/128, DD/128, 2), 256, 0, stream>>>(ao, wto, nullptr, nullptr, x2,
                                                          M, DD, 512, DD, DD);

  // LN2 (+ fused d_out = x2 + bf2 init for FFN2 split-K)
  ln_k<1><<<M, 256, 0, stream>>>(x2, g2, b2, h2, bf2, (float*)d_out);

  // FFN1 (r17-proven 2-phase, GELU)
  gemm32_k<1><<<dim3(M/128, DFFN/128), 256, 0, stream>>>(h2, wtf1, bf1, nullptr, ff, M, DFFN, DD, DD, DD);

  // FFN2: split-K2 atomic accumulate onto d_out (= x2 + bf2 from LN2)
  gemm32_k<5><<<dim3(M/128, DD/128, 2), 256, 0, stream>>>(ff, wtf2, nullptr, nullptr, (float*)d_out,
                                                          M, DD, 2048, DFFN, DFFN);
}